// Round 2
// baseline (442.221 us; speedup 1.0000x reference)
//
#include <hip/hip_runtime.h>

typedef unsigned short u16;
typedef __attribute__((ext_vector_type(8))) unsigned short ushort8;
typedef __attribute__((ext_vector_type(8))) __bf16 bf16x8;
typedef __attribute__((ext_vector_type(4))) float f32x4;

#define T_SEQ 2048
#define WINDOW 1024

static __device__ __forceinline__ u16 f2bf(float f) {
    unsigned int u = __float_as_uint(f);
    u += 0x7fffu + ((u >> 16) & 1u);
    return (u16)(u >> 16);
}
static __device__ __forceinline__ float bf2f(u16 h) {
    return __uint_as_float(((unsigned int)h) << 16);
}
static __device__ __forceinline__ bf16x8 ld_bf8(const u16* p) {
    return __builtin_bit_cast(bf16x8, *(const ushort8*)p);
}

// ---------------- QKV GEMM: C[4096 x 3072] = x[4096 x 2048] @ [Wq|Wk|Wv] ----------------
__global__ __launch_bounds__(256)
void qkv_gemm(const float* __restrict__ x,
              const float* __restrict__ Wq, const float* __restrict__ Wk,
              const float* __restrict__ Wv,
              u16* __restrict__ Qb, u16* __restrict__ Kb, u16* __restrict__ Vb)
{
    const int K = 2048;
    __shared__ __align__(16) u16 Al[128][40];
    __shared__ __align__(16) u16 Bl[128][40];
    const int tid = threadIdx.x;
    const int lane = tid & 63;
    const int w = tid >> 6;
    const int wm = w >> 1, wn = w & 1;
    const int m0 = blockIdx.x * 128;
    const int n0g = blockIdx.y * 128;

    const float* Bsrc; int ldb; int nb;
    if (n0g < 2048)      { Bsrc = Wq; ldb = 2048; nb = n0g; }
    else if (n0g < 2560) { Bsrc = Wk; ldb = 512;  nb = n0g - 2048; }
    else                 { Bsrc = Wv; ldb = 512;  nb = n0g - 2560; }

    f32x4 acc[4][4] = {};

    const int ar = tid >> 1;
    const int ak = (tid & 1) * 16;
    const int bn = tid & 127;
    const int bk0 = (tid >> 7) * 16;

    for (int kb = 0; kb < K; kb += 32) {
        // stage A (fp32 -> bf16), vectorized
        {
            const float* ag = x + (size_t)(m0 + ar) * K + kb + ak;
            float4 v0 = *(const float4*)(ag + 0);
            float4 v1 = *(const float4*)(ag + 4);
            float4 v2 = *(const float4*)(ag + 8);
            float4 v3 = *(const float4*)(ag + 12);
            ushort8 s0 = { f2bf(v0.x), f2bf(v0.y), f2bf(v0.z), f2bf(v0.w),
                           f2bf(v1.x), f2bf(v1.y), f2bf(v1.z), f2bf(v1.w) };
            ushort8 s1 = { f2bf(v2.x), f2bf(v2.y), f2bf(v2.z), f2bf(v2.w),
                           f2bf(v3.x), f2bf(v3.y), f2bf(v3.z), f2bf(v3.w) };
            *(ushort8*)&Al[ar][ak]     = s0;
            *(ushort8*)&Al[ar][ak + 8] = s1;
        }
        // stage B transposed: gather strided, write vectorized
        {
            const float* bg = Bsrc + (size_t)(kb + bk0) * ldb + nb + bn;
            float t[16];
            #pragma unroll
            for (int i = 0; i < 16; ++i) t[i] = bg[(size_t)i * ldb];
            ushort8 s0 = { f2bf(t[0]), f2bf(t[1]), f2bf(t[2]), f2bf(t[3]),
                           f2bf(t[4]), f2bf(t[5]), f2bf(t[6]), f2bf(t[7]) };
            ushort8 s1 = { f2bf(t[8]), f2bf(t[9]), f2bf(t[10]), f2bf(t[11]),
                           f2bf(t[12]), f2bf(t[13]), f2bf(t[14]), f2bf(t[15]) };
            *(ushort8*)&Bl[bn][bk0]     = s0;
            *(ushort8*)&Bl[bn][bk0 + 8] = s1;
        }
        __syncthreads();

        bf16x8 af[4], bfr[4];
        #pragma unroll
        for (int m = 0; m < 4; ++m)
            af[m] = ld_bf8(&Al[wm * 64 + m * 16 + (lane & 15)][(lane >> 4) * 8]);
        #pragma unroll
        for (int n = 0; n < 4; ++n)
            bfr[n] = ld_bf8(&Bl[wn * 64 + n * 16 + (lane & 15)][(lane >> 4) * 8]);
        #pragma unroll
        for (int m = 0; m < 4; ++m)
            #pragma unroll
            for (int n = 0; n < 4; ++n)
                acc[m][n] = __builtin_amdgcn_mfma_f32_16x16x32_bf16(af[m], bfr[n], acc[m][n], 0, 0, 0);
        __syncthreads();
    }

    const int r0 = (lane >> 4) * 4;
    const int c0 = lane & 15;
    #pragma unroll
    for (int m = 0; m < 4; ++m) {
        #pragma unroll
        for (int n = 0; n < 4; ++n) {
            #pragma unroll
            for (int r = 0; r < 4; ++r) {
                int row = m0 + wm * 64 + m * 16 + r0 + r;
                int col = n0g + wn * 64 + n * 16 + c0;
                float v = acc[m][n][r];
                int b = row >> 11, t = row & 2047;
                if (col < 2048) {
                    int h = col >> 6, d = col & 63;
                    Qb[(((size_t)b * 32 + h) * 2048 + t) * 64 + d] = f2bf(v);
                } else if (col < 2560) {
                    int c2 = col - 2048; int hk = c2 >> 6, d = c2 & 63;
                    Kb[(((size_t)b * 8 + hk) * 2048 + t) * 64 + d] = f2bf(v);
                } else {
                    int c2 = col - 2560; int hk = c2 >> 6, d = c2 & 63;
                    Vb[(((size_t)b * 8 + hk) * 2048 + t) * 64 + d] = f2bf(v);
                }
            }
        }
    }
}

// ---------------- RoPE in-place on Q and K ----------------
__global__ __launch_bounds__(256)
void rope_kernel(u16* __restrict__ Qb, u16* __restrict__ Kb)
{
    const int QP = 2 * 32 * 2048 * 32;
    const int KP = 2 * 8 * 2048 * 32;
    int idx = blockIdx.x * 256 + threadIdx.x;
    if (idx >= QP + KP) return;
    u16* buf; int p;
    if (idx < QP) { buf = Qb; p = idx; } else { buf = Kb; p = idx - QP; }
    int dp = p & 31;
    int t = (p >> 5) & 2047;
    int bh = p >> 16;
    size_t base = ((size_t)bh * 2048 + t) * 64 + dp;
    float x1 = bf2f(buf[base]);
    float x2 = bf2f(buf[base + 32]);
    float inv_freq = __expf(-dp * 0.28782313662425574f); // ln(10000)/32
    float ang = (float)t * inv_freq;
    float s, c;
    sincosf(ang, &s, &c);
    buf[base]      = f2bf(x1 * c - x2 * s);
    buf[base + 32] = f2bf(x2 * c + x1 * s);
}

// ---------------- V transpose: (b,hk,t,d) -> (b,hk,d,t) ----------------
__global__ __launch_bounds__(256)
void vtrans(const u16* __restrict__ Vb, u16* __restrict__ Vt)
{
    __shared__ __align__(16) u16 tile[64][68];
    const int tid = threadIdx.x;
    const int t0 = blockIdx.x * 64;
    const size_t base = (size_t)blockIdx.y * 2048 * 64;
    {
        int r = tid >> 2, c0 = (tid & 3) * 16;
        const u16* src = Vb + base + (size_t)(t0 + r) * 64 + c0;
        *(ushort8*)&tile[r][c0]     = *(const ushort8*)src;
        *(ushort8*)&tile[r][c0 + 8] = *(const ushort8*)(src + 8);
    }
    __syncthreads();
    {
        int d = tid >> 2, j0 = (tid & 3) * 16;
        ushort8 o0, o1;
        #pragma unroll
        for (int i = 0; i < 8; ++i) o0[i] = tile[j0 + i][d];
        #pragma unroll
        for (int i = 0; i < 8; ++i) o1[i] = tile[j0 + 8 + i][d];
        u16* dst = Vt + base + (size_t)d * 2048 + t0 + j0;
        *(ushort8*)dst       = o0;
        *(ushort8*)(dst + 8) = o1;
    }
}

// ---------------- Flash attention, sliding window, KVBLK=128 ----------------
__global__ __launch_bounds__(256)
void attn_kernel(const u16* __restrict__ Qb, const u16* __restrict__ Kb,
                 const u16* __restrict__ Vt, u16* __restrict__ AO)
{
    __shared__ __align__(16) u16 Kl[128][72];
    __shared__ __align__(16) u16 Vl[64][132];    // Vl[d][j]
    __shared__ __align__(16) u16 Pl[4][16][132];

    const int tid = threadIdx.x;
    const int lane = tid & 63;
    const int w = tid >> 6;
    const int q0 = blockIdx.x * 64;
    const int bh = blockIdx.y;
    const int b = bh >> 5, h = bh & 31;
    const int hk = h >> 2;
    const size_t qbase = (size_t)bh * 2048 * 64;
    const size_t kbase = ((size_t)b * 8 + hk) * 2048 * 64;
    const size_t vbase = ((size_t)b * 8 + hk) * 2048 * 64;  // Vt: [d][t]

    // Q fragments, pre-scaled by 1/8 (exact in bf16)
    bf16x8 qf0, qf1;
    {
        const u16* qp = Qb + qbase + (size_t)(q0 + w * 16 + (lane & 15)) * 64 + ((lane >> 4) * 8);
        ushort8 r0 = *(const ushort8*)qp;
        ushort8 r1 = *(const ushort8*)(qp + 32);
        ushort8 q0s, q1s;
        #pragma unroll
        for (int e = 0; e < 8; ++e) {
            q0s[e] = f2bf(bf2f(r0[e]) * 0.125f);
            q1s[e] = f2bf(bf2f(r1[e]) * 0.125f);
        }
        qf0 = __builtin_bit_cast(bf16x8, q0s);
        qf1 = __builtin_bit_cast(bf16x8, q1s);
    }

    float mrun[4], lrun[4];
    f32x4 o[4] = {};
    #pragma unroll
    for (int r = 0; r < 4; ++r) { mrun[r] = -1e20f; lrun[r] = 0.f; }

    int kbeg = q0 - (WINDOW - 1);
    if (kbeg < 0) kbeg = 0;
    kbeg &= ~127;

    const int wrow_min = q0 + w * 16;
    const int wrow_max = wrow_min + 15;
    const int irow_base = wrow_min + ((lane >> 4) << 2);

    for (int k0 = kbeg; k0 < q0 + 64; k0 += 128) {
        // ---- stage K tile: 128 rows x 64 d, vectorized ----
        {
            int j = tid >> 2;
            int d0 = (tid & 3) * 16;
            #pragma unroll
            for (int jj = 0; jj < 2; ++jj) {
                int r = j + jj * 64;
                const u16* kg = Kb + kbase + (size_t)(k0 + r) * 64 + d0;
                *(ushort8*)&Kl[r][d0]     = *(const ushort8*)kg;
                *(ushort8*)&Kl[r][d0 + 8] = *(const ushort8*)(kg + 8);
            }
        }
        // ---- stage V tile from transposed global: Vl[d][j], vectorized ----
        {
            int d = tid >> 2;
            int j0 = (tid & 3) * 32;
            const u16* vg = Vt + vbase + (size_t)d * 2048 + k0 + j0;
            *(ushort8*)&Vl[d][j0]      = *(const ushort8*)vg;
            *(ushort8*)&Vl[d][j0 + 8]  = *(const ushort8*)(vg + 8);
            *(ushort8*)&Vl[d][j0 + 16] = *(const ushort8*)(vg + 16);
            *(ushort8*)&Vl[d][j0 + 24] = *(const ushort8*)(vg + 24);
        }
        __syncthreads();

        bool any = (k0 <= wrow_max) && (k0 + 127 >= wrow_min - (WINDOW - 1));
        if (any) {
            // ---- S = Q K^T : 8 key fragments of 16 ----
            f32x4 s[8];
            #pragma unroll
            for (int nf = 0; nf < 8; ++nf) {
                bf16x8 kb0 = ld_bf8(&Kl[nf * 16 + (lane & 15)][(lane >> 4) * 8]);
                bf16x8 kb1 = ld_bf8(&Kl[nf * 16 + (lane & 15)][32 + (lane >> 4) * 8]);
                f32x4 a = {};
                a = __builtin_amdgcn_mfma_f32_16x16x32_bf16(qf0, kb0, a, 0, 0, 0);
                a = __builtin_amdgcn_mfma_f32_16x16x32_bf16(qf1, kb1, a, 0, 0, 0);
                s[nf] = a;
            }
            // ---- mask (only on boundary tiles) ----
            bool need_causal = (k0 + 127 > wrow_min);
            bool need_window = (wrow_max - k0) >= WINDOW;
            if (need_causal || need_window) {
                #pragma unroll
                for (int nf = 0; nf < 8; ++nf) {
                    int j = k0 + nf * 16 + (lane & 15);
                    #pragma unroll
                    for (int r = 0; r < 4; ++r) {
                        int i = irow_base + r;
                        bool ok = (j <= i) && (i - j < WINDOW);
                        if (!ok) s[nf][r] = -1e30f;
                    }
                }
            }
            // ---- row max ----
            float tmax[4];
            #pragma unroll
            for (int r = 0; r < 4; ++r) tmax[r] = s[0][r];
            #pragma unroll
            for (int nf = 1; nf < 8; ++nf)
                #pragma unroll
                for (int r = 0; r < 4; ++r) tmax[r] = fmaxf(tmax[r], s[nf][r]);
            #pragma unroll
            for (int off = 1; off < 16; off <<= 1)
                #pragma unroll
                for (int r = 0; r < 4; ++r)
                    tmax[r] = fmaxf(tmax[r], __shfl_xor(tmax[r], off, 64));

            float mnew[4], sc[4], tsum[4];
            #pragma unroll
            for (int r = 0; r < 4; ++r) {
                mnew[r] = fmaxf(mrun[r], tmax[r]);   // >= -1e20 always
                sc[r] = __expf(mrun[r] - mnew[r]);
                mrun[r] = mnew[r];
                tsum[r] = 0.f;
            }
            // ---- P = exp(S - m); masked (-1e30) underflows to 0 ----
            #pragma unroll
            for (int nf = 0; nf < 8; ++nf) {
                #pragma unroll
                for (int r = 0; r < 4; ++r) {
                    float p = __expf(s[nf][r] - mnew[r]);
                    tsum[r] += p;
                    Pl[w][((lane >> 4) << 2) + r][nf * 16 + (lane & 15)] = f2bf(p);
                }
            }
            #pragma unroll
            for (int off = 1; off < 16; off <<= 1)
                #pragma unroll
                for (int r = 0; r < 4; ++r)
                    tsum[r] += __shfl_xor(tsum[r], off, 64);
            #pragma unroll
            for (int r = 0; r < 4; ++r)
                lrun[r] = lrun[r] * sc[r] + tsum[r];
            #pragma unroll
            for (int nf = 0; nf < 4; ++nf)
                #pragma unroll
                for (int r = 0; r < 4; ++r)
                    o[nf][r] *= sc[r];

            // ---- O += P @ V ----
            bf16x8 pa[4];
            #pragma unroll
            for (int ks = 0; ks < 4; ++ks)
                pa[ks] = ld_bf8(&Pl[w][lane & 15][ks * 32 + (lane >> 4) * 8]);
            #pragma unroll
            for (int nf = 0; nf < 4; ++nf) {
                #pragma unroll
                for (int ks = 0; ks < 4; ++ks) {
                    bf16x8 vbf = ld_bf8(&Vl[nf * 16 + (lane & 15)][ks * 32 + (lane >> 4) * 8]);
                    o[nf] = __builtin_amdgcn_mfma_f32_16x16x32_bf16(pa[ks], vbf, o[nf], 0, 0, 0);
                }
            }
        }
        __syncthreads();
    }

    float inv[4];
    #pragma unroll
    for (int r = 0; r < 4; ++r) inv[r] = 1.f / lrun[r];
    #pragma unroll
    for (int nf = 0; nf < 4; ++nf) {
        #pragma unroll
        for (int r = 0; r < 4; ++r) {
            int i = q0 + w * 16 + ((lane >> 4) << 2) + r;
            int d = nf * 16 + (lane & 15);
            AO[((size_t)b * 2048 + i) * 2048 + h * 64 + d] = f2bf(o[nf][r] * inv[r]);
        }
    }
}

// ---------------- Output projection: out[4096 x 2048] = AO_bf16 @ Wo ----------------
__global__ __launch_bounds__(256)
void out_gemm(const u16* __restrict__ A, const float* __restrict__ Wo, float* __restrict__ C)
{
    const int K = 2048;
    __shared__ __align__(16) u16 Al[128][40];
    __shared__ __align__(16) u16 Bl[128][40];
    const int tid = threadIdx.x;
    const int lane = tid & 63;
    const int w = tid >> 6;
    const int wm = w >> 1, wn = w & 1;
    const int m0 = blockIdx.x * 128;
    const int n0 = blockIdx.y * 128;

    f32x4 acc[4][4] = {};

    const int ar = tid >> 1;
    const int ak = (tid & 1) * 16;
    const int bn = tid & 127;
    const int bk0 = (tid >> 7) * 16;

    for (int kb = 0; kb < K; kb += 32) {
        {
            const u16* ag = A + (size_t)(m0 + ar) * K + kb + ak;
            *(ushort8*)&Al[ar][ak]     = *(const ushort8*)ag;
            *(ushort8*)&Al[ar][ak + 8] = *(const ushort8*)(ag + 8);
        }
        {
            const float* bg = Wo + (size_t)(kb + bk0) * 2048 + n0 + bn;
            float t[16];
            #pragma unroll
            for (int i = 0; i < 16; ++i) t[i] = bg[(size_t)i * 2048];
            ushort8 s0 = { f2bf(t[0]), f2bf(t[1]), f2bf(t[2]), f2bf(t[3]),
                           f2bf(t[4]), f2bf(t[5]), f2bf(t[6]), f2bf(t[7]) };
            ushort8 s1 = { f2bf(t[8]), f2bf(t[9]), f2bf(t[10]), f2bf(t[11]),
                           f2bf(t[12]), f2bf(t[13]), f2bf(t[14]), f2bf(t[15]) };
            *(ushort8*)&Bl[bn][bk0]     = s0;
            *(ushort8*)&Bl[bn][bk0 + 8] = s1;
        }
        __syncthreads();

        bf16x8 af[4], bfr[4];
        #pragma unroll
        for (int m = 0; m < 4; ++m)
            af[m] = ld_bf8(&Al[wm * 64 + m * 16 + (lane & 15)][(lane >> 4) * 8]);
        #pragma unroll
        for (int n = 0; n < 4; ++n)
            bfr[n] = ld_bf8(&Bl[wn * 64 + n * 16 + (lane & 15)][(lane >> 4) * 8]);
        #pragma unroll
        for (int m = 0; m < 4; ++m)
            #pragma unroll
            for (int n = 0; n < 4; ++n)
                acc[m][n] = __builtin_amdgcn_mfma_f32_16x16x32_bf16(af[m], bfr[n], acc[m][n], 0, 0, 0);
        __syncthreads();
    }

    const int r0 = (lane >> 4) * 4;
    const int c0 = lane & 15;
    #pragma unroll
    for (int m = 0; m < 4; ++m) {
        #pragma unroll
        for (int n = 0; n < 4; ++n) {
            #pragma unroll
            for (int r = 0; r < 4; ++r) {
                int row = m0 + wm * 64 + m * 16 + r0 + r;
                int col = n0 + wn * 64 + n * 16 + c0;
                C[(size_t)row * 2048 + col] = acc[m][n][r];
            }
        }
    }
}

extern "C" void kernel_launch(void* const* d_in, const int* in_sizes, int n_in,
                              void* d_out, int out_size, void* d_ws, size_t ws_size,
                              hipStream_t stream)
{
    const float* x  = (const float*)d_in[0];
    const float* Wq = (const float*)d_in[1];
    const float* Wk = (const float*)d_in[2];
    const float* Wv = (const float*)d_in[3];
    const float* Wo = (const float*)d_in[4];
    float* out = (float*)d_out;

    u16* Qb = (u16*)d_ws;                               // 8,388,608
    u16* Kb = Qb + (size_t)2 * 32 * 2048 * 64;          // 2,097,152
    u16* Vb = Kb + (size_t)2 * 8 * 2048 * 64;           // 2,097,152
    u16* Vt = Vb + (size_t)2 * 8 * 2048 * 64;           // 2,097,152
    u16* AO = Vt + (size_t)2 * 8 * 2048 * 64;           // 8,388,608

    qkv_gemm<<<dim3(32, 24), 256, 0, stream>>>(x, Wq, Wk, Wv, Qb, Kb, Vb);
    rope_kernel<<<(4194304 + 1048576) / 256, 256, 0, stream>>>(Qb, Kb);
    vtrans<<<dim3(32, 16), 256, 0, stream>>>(Vb, Vt);
    attn_kernel<<<dim3(32, 64), 256, 0, stream>>>(Qb, Kb, Vt, AO);
    out_gemm<<<dim3(32, 16), 256, 0, stream>>>(AO, Wo, out);
}

// Round 3
// 327.261 us; speedup vs baseline: 1.3513x; 1.3513x over previous
//
#include <hip/hip_runtime.h>

typedef unsigned short u16;
typedef __attribute__((ext_vector_type(8))) unsigned short ushort8;
typedef __attribute__((ext_vector_type(8))) __bf16 bf16x8;
typedef __attribute__((ext_vector_type(4))) float f32x4;

#define T_SEQ 2048
#define WINDOW 1024

static __device__ __forceinline__ u16 f2bf(float f) {
    unsigned int u = __float_as_uint(f);
    u += 0x7fffu + ((u >> 16) & 1u);
    return (u16)(u >> 16);
}
static __device__ __forceinline__ float bf2f(u16 h) {
    return __uint_as_float(((unsigned int)h) << 16);
}
static __device__ __forceinline__ bf16x8 ld_bf8(const u16* p) {
    return __builtin_bit_cast(bf16x8, *(const ushort8*)p);
}

// ---------------- x fp32 -> bf16 (same layout) ----------------
__global__ __launch_bounds__(256)
void convert_x(const float* __restrict__ src, u16* __restrict__ dst)
{
    int i8 = blockIdx.x * 256 + threadIdx.x;   // 8 elems per thread
    size_t base = (size_t)i8 * 8;
    float4 a = *(const float4*)(src + base);
    float4 b = *(const float4*)(src + base + 4);
    ushort8 o = { f2bf(a.x), f2bf(a.y), f2bf(a.z), f2bf(a.w),
                  f2bf(b.x), f2bf(b.y), f2bf(b.z), f2bf(b.w) };
    *(ushort8*)(dst + base) = o;
}

// ---------------- W fp32 [2048][N] -> bf16 transposed [N][2048] ----------------
__global__ __launch_bounds__(256)
void trans_conv(const float* __restrict__ src, int N, u16* __restrict__ dst)
{
    __shared__ __align__(16) u16 tile[64][72];
    const int tid = threadIdx.x;
    const int k0 = blockIdx.x * 64;
    const int n0 = blockIdx.y * 64;
    {
        int r = tid >> 2, c0 = (tid & 3) * 16;
        const float* sp = src + (size_t)(k0 + r) * N + n0 + c0;
        float4 v0 = *(const float4*)(sp + 0);
        float4 v1 = *(const float4*)(sp + 4);
        float4 v2 = *(const float4*)(sp + 8);
        float4 v3 = *(const float4*)(sp + 12);
        ushort8 s0 = { f2bf(v0.x), f2bf(v0.y), f2bf(v0.z), f2bf(v0.w),
                       f2bf(v1.x), f2bf(v1.y), f2bf(v1.z), f2bf(v1.w) };
        ushort8 s1 = { f2bf(v2.x), f2bf(v2.y), f2bf(v2.z), f2bf(v2.w),
                       f2bf(v3.x), f2bf(v3.y), f2bf(v3.z), f2bf(v3.w) };
        *(ushort8*)&tile[r][c0]     = s0;
        *(ushort8*)&tile[r][c0 + 8] = s1;
    }
    __syncthreads();
    {
        int n = tid >> 2, j0 = (tid & 3) * 16;
        ushort8 o0, o1;
        #pragma unroll
        for (int i = 0; i < 8; ++i) o0[i] = tile[j0 + i][n];
        #pragma unroll
        for (int i = 0; i < 8; ++i) o1[i] = tile[j0 + 8 + i][n];
        u16* dp = dst + (size_t)(n0 + n) * 2048 + k0 + j0;
        *(ushort8*)dp       = o0;
        *(ushort8*)(dp + 8) = o1;
    }
}

// ---------------- QKV GEMM (bf16 in): C[4096 x 3072] = xb @ WqkvT^T ----------------
__global__ __launch_bounds__(256)
void qkv_gemm(const u16* __restrict__ xb, const u16* __restrict__ Wt,
              u16* __restrict__ Qb, u16* __restrict__ Kb, u16* __restrict__ Vb)
{
    __shared__ __align__(16) u16 Al[128][72];
    __shared__ __align__(16) u16 Bl[128][72];
    const int tid = threadIdx.x;
    const int lane = tid & 63;
    const int w = tid >> 6;
    const int wm = w >> 1, wn = w & 1;
    const int m0 = blockIdx.x * 128;
    const int n0g = blockIdx.y * 128;

    f32x4 acc[4][4] = {};
    const int row = tid & 127;
    const int kh = (tid >> 7) * 32;

    for (int kb = 0; kb < 2048; kb += 64) {
        const u16* ag = xb + (size_t)(m0 + row) * 2048 + kb + kh;
        const u16* bg = Wt + (size_t)(n0g + row) * 2048 + kb + kh;
        #pragma unroll
        for (int i = 0; i < 4; ++i)
            *(ushort8*)&Al[row][kh + i * 8] = *(const ushort8*)(ag + i * 8);
        #pragma unroll
        for (int i = 0; i < 4; ++i)
            *(ushort8*)&Bl[row][kh + i * 8] = *(const ushort8*)(bg + i * 8);
        __syncthreads();

        #pragma unroll
        for (int kc = 0; kc < 2; ++kc) {
            bf16x8 af[4], bfr[4];
            #pragma unroll
            for (int m = 0; m < 4; ++m)
                af[m] = ld_bf8(&Al[wm * 64 + m * 16 + (lane & 15)][kc * 32 + (lane >> 4) * 8]);
            #pragma unroll
            for (int n = 0; n < 4; ++n)
                bfr[n] = ld_bf8(&Bl[wn * 64 + n * 16 + (lane & 15)][kc * 32 + (lane >> 4) * 8]);
            #pragma unroll
            for (int m = 0; m < 4; ++m)
                #pragma unroll
                for (int n = 0; n < 4; ++n)
                    acc[m][n] = __builtin_amdgcn_mfma_f32_16x16x32_bf16(af[m], bfr[n], acc[m][n], 0, 0, 0);
        }
        __syncthreads();
    }

    const int r0 = (lane >> 4) * 4;
    const int c0 = lane & 15;
    #pragma unroll
    for (int m = 0; m < 4; ++m) {
        #pragma unroll
        for (int n = 0; n < 4; ++n) {
            #pragma unroll
            for (int r = 0; r < 4; ++r) {
                int rw = m0 + wm * 64 + m * 16 + r0 + r;
                int col = n0g + wn * 64 + n * 16 + c0;
                float v = acc[m][n][r];
                int b = rw >> 11, t = rw & 2047;
                if (col < 2048) {
                    int h = col >> 6, d = col & 63;
                    Qb[(((size_t)b * 32 + h) * 2048 + t) * 64 + d] = f2bf(v);
                } else if (col < 2560) {
                    int c2 = col - 2048; int hk = c2 >> 6, d = c2 & 63;
                    Kb[(((size_t)b * 8 + hk) * 2048 + t) * 64 + d] = f2bf(v);
                } else {
                    int c2 = col - 2560; int hk = c2 >> 6, d = c2 & 63;
                    Vb[(((size_t)b * 8 + hk) * 2048 + t) * 64 + d] = f2bf(v);
                }
            }
        }
    }
}

// ---------------- RoPE in-place on Q and K ----------------
__global__ __launch_bounds__(256)
void rope_kernel(u16* __restrict__ Qb, u16* __restrict__ Kb)
{
    const int QP = 2 * 32 * 2048 * 32;
    const int KP = 2 * 8 * 2048 * 32;
    int idx = blockIdx.x * 256 + threadIdx.x;
    if (idx >= QP + KP) return;
    u16* buf; int p;
    if (idx < QP) { buf = Qb; p = idx; } else { buf = Kb; p = idx - QP; }
    int dp = p & 31;
    int t = (p >> 5) & 2047;
    int bh = p >> 16;
    size_t base = ((size_t)bh * 2048 + t) * 64 + dp;
    float x1 = bf2f(buf[base]);
    float x2 = bf2f(buf[base + 32]);
    float inv_freq = __expf(-dp * 0.28782313662425574f); // ln(10000)/32
    float ang = (float)t * inv_freq;
    float s, c;
    sincosf(ang, &s, &c);
    buf[base]      = f2bf(x1 * c - x2 * s);
    buf[base + 32] = f2bf(x2 * c + x1 * s);
}

// ---------------- V transpose: (b,hk,t,d) -> (b,hk,d,t) ----------------
__global__ __launch_bounds__(256)
void vtrans(const u16* __restrict__ Vb, u16* __restrict__ Vt)
{
    __shared__ __align__(16) u16 tile[64][68];
    const int tid = threadIdx.x;
    const int t0 = blockIdx.x * 64;
    const size_t base = (size_t)blockIdx.y * 2048 * 64;
    {
        int r = tid >> 2, c0 = (tid & 3) * 16;
        const u16* src = Vb + base + (size_t)(t0 + r) * 64 + c0;
        *(ushort8*)&tile[r][c0]     = *(const ushort8*)src;
        *(ushort8*)&tile[r][c0 + 8] = *(const ushort8*)(src + 8);
    }
    __syncthreads();
    {
        int d = tid >> 2, j0 = (tid & 3) * 16;
        ushort8 o0, o1;
        #pragma unroll
        for (int i = 0; i < 8; ++i) o0[i] = tile[j0 + i][d];
        #pragma unroll
        for (int i = 0; i < 8; ++i) o1[i] = tile[j0 + 8 + i][d];
        u16* dst = Vt + base + (size_t)d * 2048 + t0 + j0;
        *(ushort8*)dst       = o0;
        *(ushort8*)(dst + 8) = o1;
    }
}

// ---------------- Flash attention, KVBLK=64, async-stage split (T14) ----------------
__global__ __launch_bounds__(256)
void attn_kernel(const u16* __restrict__ Qb, const u16* __restrict__ Kb,
                 const u16* __restrict__ Vt, u16* __restrict__ AO)
{
    __shared__ __align__(16) u16 Kl[64][72];
    __shared__ __align__(16) u16 Vl[64][72];    // Vl[d][j]
    __shared__ __align__(16) u16 Pl[4][16][72];

    const int tid = threadIdx.x;
    const int lane = tid & 63;
    const int w = tid >> 6;
    const int q0 = blockIdx.x * 64;
    const int bh = blockIdx.y;
    const int b = bh >> 5, h = bh & 31;
    const int hk = h >> 2;
    const size_t qbase = (size_t)bh * 2048 * 64;
    const size_t kbase = ((size_t)b * 8 + hk) * 2048 * 64;
    const size_t vbase = ((size_t)b * 8 + hk) * 2048 * 64;  // Vt: [d][t]

    // staging geometry (shared by K and V)
    const int sj = tid >> 2;              // K row / V d-row: 0..63
    const int sd = (tid & 3) * 16;        // 16-elem chunk

    // Q fragments, pre-scaled by 1/8 (exact in bf16)
    bf16x8 qf0, qf1;
    {
        const u16* qp = Qb + qbase + (size_t)(q0 + w * 16 + (lane & 15)) * 64 + ((lane >> 4) * 8);
        ushort8 r0 = *(const ushort8*)qp;
        ushort8 r1 = *(const ushort8*)(qp + 32);
        ushort8 q0s, q1s;
        #pragma unroll
        for (int e = 0; e < 8; ++e) {
            q0s[e] = f2bf(bf2f(r0[e]) * 0.125f);
            q1s[e] = f2bf(bf2f(r1[e]) * 0.125f);
        }
        qf0 = __builtin_bit_cast(bf16x8, q0s);
        qf1 = __builtin_bit_cast(bf16x8, q1s);
    }

    float mrun[4], lrun[4];
    f32x4 o[4] = {};
    #pragma unroll
    for (int r = 0; r < 4; ++r) { mrun[r] = -1e20f; lrun[r] = 0.f; }

    int kbeg = q0 - (WINDOW - 1);
    if (kbeg < 0) kbeg = 0;
    kbeg &= ~63;
    const int kend = q0 + 64;

    const int wrow_min = q0 + w * 16;
    const int wrow_max = wrow_min + 15;
    const int irow_base = wrow_min + ((lane >> 4) << 2);

    // prologue: stage first tile
    ushort8 kr0, kr1, vr0, vr1;
    {
        const u16* kg = Kb + kbase + (size_t)(kbeg + sj) * 64 + sd;
        kr0 = *(const ushort8*)kg;
        kr1 = *(const ushort8*)(kg + 8);
        const u16* vg = Vt + vbase + (size_t)sj * 2048 + kbeg + sd;
        vr0 = *(const ushort8*)vg;
        vr1 = *(const ushort8*)(vg + 8);
    }
    *(ushort8*)&Kl[sj][sd]     = kr0;
    *(ushort8*)&Kl[sj][sd + 8] = kr1;
    *(ushort8*)&Vl[sj][sd]     = vr0;
    *(ushort8*)&Vl[sj][sd + 8] = vr1;
    __syncthreads();

    for (int k0 = kbeg; k0 < kend; k0 += 64) {
        const bool has_next = (k0 + 64 < kend);
        // issue next tile's global loads (latency hides under compute)
        if (has_next) {
            const u16* kg = Kb + kbase + (size_t)(k0 + 64 + sj) * 64 + sd;
            kr0 = *(const ushort8*)kg;
            kr1 = *(const ushort8*)(kg + 8);
            const u16* vg = Vt + vbase + (size_t)sj * 2048 + k0 + 64 + sd;
            vr0 = *(const ushort8*)vg;
            vr1 = *(const ushort8*)(vg + 8);
        }

        bool active = (k0 <= wrow_max) && (k0 + 63 >= wrow_min - (WINDOW - 1));
        if (active) {
            // ---- S = Q K^T ----
            f32x4 s[4];
            #pragma unroll
            for (int nf = 0; nf < 4; ++nf) {
                bf16x8 kb0 = ld_bf8(&Kl[nf * 16 + (lane & 15)][(lane >> 4) * 8]);
                bf16x8 kb1 = ld_bf8(&Kl[nf * 16 + (lane & 15)][32 + (lane >> 4) * 8]);
                f32x4 a = {};
                a = __builtin_amdgcn_mfma_f32_16x16x32_bf16(qf0, kb0, a, 0, 0, 0);
                a = __builtin_amdgcn_mfma_f32_16x16x32_bf16(qf1, kb1, a, 0, 0, 0);
                s[nf] = a;
            }
            // ---- boundary-only masking ----
            bool need_causal = (k0 + 63 > wrow_min);
            bool need_window = (wrow_max - k0) >= WINDOW;
            if (need_causal || need_window) {
                #pragma unroll
                for (int nf = 0; nf < 4; ++nf) {
                    int j = k0 + nf * 16 + (lane & 15);
                    #pragma unroll
                    for (int r = 0; r < 4; ++r) {
                        int i = irow_base + r;
                        bool ok = (j <= i) && (i - j < WINDOW);
                        if (!ok) s[nf][r] = -1e30f;
                    }
                }
            }
            // ---- row max ----
            float tmax[4];
            #pragma unroll
            for (int r = 0; r < 4; ++r) tmax[r] = s[0][r];
            #pragma unroll
            for (int nf = 1; nf < 4; ++nf)
                #pragma unroll
                for (int r = 0; r < 4; ++r) tmax[r] = fmaxf(tmax[r], s[nf][r]);
            #pragma unroll
            for (int off = 1; off < 16; off <<= 1)
                #pragma unroll
                for (int r = 0; r < 4; ++r)
                    tmax[r] = fmaxf(tmax[r], __shfl_xor(tmax[r], off, 64));

            float mnew[4], sc[4], tsum[4];
            #pragma unroll
            for (int r = 0; r < 4; ++r) {
                mnew[r] = fmaxf(mrun[r], tmax[r]);
                sc[r] = __expf(mrun[r] - mnew[r]);
                mrun[r] = mnew[r];
                tsum[r] = 0.f;
            }
            // ---- P = exp(S - m) ----
            #pragma unroll
            for (int nf = 0; nf < 4; ++nf) {
                #pragma unroll
                for (int r = 0; r < 4; ++r) {
                    float p = __expf(s[nf][r] - mnew[r]);
                    tsum[r] += p;
                    Pl[w][((lane >> 4) << 2) + r][nf * 16 + (lane & 15)] = f2bf(p);
                }
            }
            #pragma unroll
            for (int off = 1; off < 16; off <<= 1)
                #pragma unroll
                for (int r = 0; r < 4; ++r)
                    tsum[r] += __shfl_xor(tsum[r], off, 64);
            #pragma unroll
            for (int r = 0; r < 4; ++r)
                lrun[r] = lrun[r] * sc[r] + tsum[r];
            #pragma unroll
            for (int nf = 0; nf < 4; ++nf)
                #pragma unroll
                for (int r = 0; r < 4; ++r)
                    o[nf][r] *= sc[r];

            // ---- O += P @ V ----
            bf16x8 pa0 = ld_bf8(&Pl[w][lane & 15][(lane >> 4) * 8]);
            bf16x8 pa1 = ld_bf8(&Pl[w][lane & 15][32 + (lane >> 4) * 8]);
            #pragma unroll
            for (int nf = 0; nf < 4; ++nf) {
                bf16x8 vb0 = ld_bf8(&Vl[nf * 16 + (lane & 15)][(lane >> 4) * 8]);
                bf16x8 vb1 = ld_bf8(&Vl[nf * 16 + (lane & 15)][32 + (lane >> 4) * 8]);
                o[nf] = __builtin_amdgcn_mfma_f32_16x16x32_bf16(pa0, vb0, o[nf], 0, 0, 0);
                o[nf] = __builtin_amdgcn_mfma_f32_16x16x32_bf16(pa1, vb1, o[nf], 0, 0, 0);
            }
        }
        __syncthreads();   // all waves done reading Kl/Vl
        if (has_next) {
            *(ushort8*)&Kl[sj][sd]     = kr0;
            *(ushort8*)&Kl[sj][sd + 8] = kr1;
            *(ushort8*)&Vl[sj][sd]     = vr0;
            *(ushort8*)&Vl[sj][sd + 8] = vr1;
        }
        __syncthreads();   // stage complete
    }

    float inv[4];
    #pragma unroll
    for (int r = 0; r < 4; ++r) inv[r] = 1.f / lrun[r];
    #pragma unroll
    for (int nf = 0; nf < 4; ++nf) {
        #pragma unroll
        for (int r = 0; r < 4; ++r) {
            int i = q0 + w * 16 + ((lane >> 4) << 2) + r;
            int d = nf * 16 + (lane & 15);
            AO[((size_t)b * 2048 + i) * 2048 + h * 64 + d] = f2bf(o[nf][r] * inv[r]);
        }
    }
}

// ---------------- Output projection: out[4096 x 2048] = AO_bf16 @ WoT^T ----------------
__global__ __launch_bounds__(256)
void out_gemm(const u16* __restrict__ A, const u16* __restrict__ Wt, float* __restrict__ C)
{
    __shared__ __align__(16) u16 Al[128][72];
    __shared__ __align__(16) u16 Bl[128][72];
    const int tid = threadIdx.x;
    const int lane = tid & 63;
    const int w = tid >> 6;
    const int wm = w >> 1, wn = w & 1;
    const int m0 = blockIdx.x * 128;
    const int n0 = blockIdx.y * 128;

    f32x4 acc[4][4] = {};
    const int row = tid & 127;
    const int kh = (tid >> 7) * 32;

    for (int kb = 0; kb < 2048; kb += 64) {
        const u16* ag = A  + (size_t)(m0 + row) * 2048 + kb + kh;
        const u16* bg = Wt + (size_t)(n0 + row) * 2048 + kb + kh;
        #pragma unroll
        for (int i = 0; i < 4; ++i)
            *(ushort8*)&Al[row][kh + i * 8] = *(const ushort8*)(ag + i * 8);
        #pragma unroll
        for (int i = 0; i < 4; ++i)
            *(ushort8*)&Bl[row][kh + i * 8] = *(const ushort8*)(bg + i * 8);
        __syncthreads();

        #pragma unroll
        for (int kc = 0; kc < 2; ++kc) {
            bf16x8 af[4], bfr[4];
            #pragma unroll
            for (int m = 0; m < 4; ++m)
                af[m] = ld_bf8(&Al[wm * 64 + m * 16 + (lane & 15)][kc * 32 + (lane >> 4) * 8]);
            #pragma unroll
            for (int n = 0; n < 4; ++n)
                bfr[n] = ld_bf8(&Bl[wn * 64 + n * 16 + (lane & 15)][kc * 32 + (lane >> 4) * 8]);
            #pragma unroll
            for (int m = 0; m < 4; ++m)
                #pragma unroll
                for (int n = 0; n < 4; ++n)
                    acc[m][n] = __builtin_amdgcn_mfma_f32_16x16x32_bf16(af[m], bfr[n], acc[m][n], 0, 0, 0);
        }
        __syncthreads();
    }

    const int r0 = (lane >> 4) * 4;
    const int c0 = lane & 15;
    #pragma unroll
    for (int m = 0; m < 4; ++m) {
        #pragma unroll
        for (int n = 0; n < 4; ++n) {
            #pragma unroll
            for (int r = 0; r < 4; ++r) {
                int rw = m0 + wm * 64 + m * 16 + r0 + r;
                int col = n0 + wn * 64 + n * 16 + c0;
                C[(size_t)rw * 2048 + col] = acc[m][n][r];
            }
        }
    }
}

extern "C" void kernel_launch(void* const* d_in, const int* in_sizes, int n_in,
                              void* d_out, int out_size, void* d_ws, size_t ws_size,
                              hipStream_t stream)
{
    const float* x  = (const float*)d_in[0];
    const float* Wq = (const float*)d_in[1];
    const float* Wk = (const float*)d_in[2];
    const float* Wv = (const float*)d_in[3];
    const float* Wo = (const float*)d_in[4];
    float* out = (float*)d_out;

    u16* Qb    = (u16*)d_ws;                              //  8,388,608
    u16* Kb    = Qb    + (size_t)8388608;                 //  2,097,152
    u16* Vb    = Kb    + (size_t)2097152;                 //  2,097,152
    u16* Vt    = Vb    + (size_t)2097152;                 //  2,097,152
    u16* AO    = Vt    + (size_t)2097152;                 //  8,388,608
    u16* xb    = AO    + (size_t)8388608;                 //  8,388,608
    u16* WqkvT = xb    + (size_t)8388608;                 //  6,291,456  [3072][2048]
    u16* WoT   = WqkvT + (size_t)6291456;                 //  4,194,304  [2048][2048]

    convert_x<<<4096, 256, 0, stream>>>(x, xb);
    trans_conv<<<dim3(32, 32), 256, 0, stream>>>(Wq, 2048, WqkvT);
    trans_conv<<<dim3(32,  8), 256, 0, stream>>>(Wk,  512, WqkvT + (size_t)2048 * 2048);
    trans_conv<<<dim3(32,  8), 256, 0, stream>>>(Wv,  512, WqkvT + (size_t)2560 * 2048);
    trans_conv<<<dim3(32, 32), 256, 0, stream>>>(Wo, 2048, WoT);

    qkv_gemm<<<dim3(32, 24), 256, 0, stream>>>(xb, WqkvT, Qb, Kb, Vb);
    rope_kernel<<<(4194304 + 1048576) / 256, 256, 0, stream>>>(Qb, Kb);
    vtrans<<<dim3(32, 16), 256, 0, stream>>>(Vb, Vt);
    attn_kernel<<<dim3(32, 64), 256, 0, stream>>>(Qb, Kb, Vt, AO);
    out_gemm<<<dim3(32, 16), 256, 0, stream>>>(AO, WoT, out);
}

// Round 5
// 233.676 us; speedup vs baseline: 1.8925x; 1.4005x over previous
//
#include <hip/hip_runtime.h>

typedef unsigned short u16;
typedef __attribute__((ext_vector_type(4))) unsigned short u16x4;
typedef __attribute__((ext_vector_type(8))) unsigned short u16x8;
typedef __attribute__((ext_vector_type(8))) __bf16 bf16x8;
typedef __attribute__((ext_vector_type(4))) float f32x4;

#define T_SEQ 2048
#define WINDOW 1024

static __device__ __forceinline__ u16 f2bf(float f) {
    unsigned int u = __float_as_uint(f);
    u += 0x7fffu + ((u >> 16) & 1u);
    return (u16)(u >> 16);
}
static __device__ __forceinline__ float bf2f(u16 h) {
    return __uint_as_float(((unsigned int)h) << 16);
}
static __device__ __forceinline__ bf16x8 ld_bf8(const u16* p) {
    return __builtin_bit_cast(bf16x8, *(const u16x8*)p);
}
// async global -> LDS, 16B per lane (wave-uniform LDS base + lane*16)
static __device__ __forceinline__ void g2l16(const void* g, void* l) {
    __builtin_amdgcn_global_load_lds(
        (const __attribute__((address_space(1))) void*)g,
        (__attribute__((address_space(3))) void*)l, 16, 0, 0);
}

// ---------------- x fp32 -> bf16 (same layout) ----------------
__global__ __launch_bounds__(256)
void convert_x(const float* __restrict__ src, u16* __restrict__ dst)
{
    int i8 = blockIdx.x * 256 + threadIdx.x;
    size_t base = (size_t)i8 * 8;
    float4 a = *(const float4*)(src + base);
    float4 b = *(const float4*)(src + base + 4);
    u16x8 o = { f2bf(a.x), f2bf(a.y), f2bf(a.z), f2bf(a.w),
                f2bf(b.x), f2bf(b.y), f2bf(b.z), f2bf(b.w) };
    *(u16x8*)(dst + base) = o;
}

// ---------------- W fp32 [2048][N] -> bf16 transposed [N][2048] ----------------
__global__ __launch_bounds__(256)
void trans_conv(const float* __restrict__ src, int N, u16* __restrict__ dst)
{
    __shared__ __align__(16) u16 tile[64][72];
    const int tid = threadIdx.x;
    const int k0 = blockIdx.x * 64;
    const int n0 = blockIdx.y * 64;
    {
        int r = tid >> 2, c0 = (tid & 3) * 16;
        const float* sp = src + (size_t)(k0 + r) * N + n0 + c0;
        float4 v0 = *(const float4*)(sp + 0);
        float4 v1 = *(const float4*)(sp + 4);
        float4 v2 = *(const float4*)(sp + 8);
        float4 v3 = *(const float4*)(sp + 12);
        u16x8 s0 = { f2bf(v0.x), f2bf(v0.y), f2bf(v0.z), f2bf(v0.w),
                     f2bf(v1.x), f2bf(v1.y), f2bf(v1.z), f2bf(v1.w) };
        u16x8 s1 = { f2bf(v2.x), f2bf(v2.y), f2bf(v2.z), f2bf(v2.w),
                     f2bf(v3.x), f2bf(v3.y), f2bf(v3.z), f2bf(v3.w) };
        *(u16x8*)&tile[r][c0]     = s0;
        *(u16x8*)&tile[r][c0 + 8] = s1;
    }
    __syncthreads();
    {
        int n = tid >> 2, j0 = (tid & 3) * 16;
        u16x8 o0, o1;
        #pragma unroll
        for (int i = 0; i < 8; ++i) o0[i] = tile[j0 + i][n];
        #pragma unroll
        for (int i = 0; i < 8; ++i) o1[i] = tile[j0 + 8 + i][n];
        u16* dp = dst + (size_t)(n0 + n) * 2048 + k0 + j0;
        *(u16x8*)dp       = o0;
        *(u16x8*)(dp + 8) = o1;
    }
}

// ---------------- QKV GEMM (m97 structure): C[4096x3072] = xb @ WqkvT^T ----------------
__global__ __launch_bounds__(256)
void qkv_gemm(const u16* __restrict__ xb, const u16* __restrict__ Wt,
              u16* __restrict__ Qb, u16* __restrict__ Kb, u16* __restrict__ Vb)
{
    __shared__ __align__(16) u16 Al[128][32];
    __shared__ __align__(16) u16 Bl[128][32];
    const int tid = threadIdx.x;
    const int lane = tid & 63;
    const int w = tid >> 6;
    const int wm = w >> 1, wn = w & 1;
    const int m0 = blockIdx.x * 128;
    const int n0g = blockIdx.y * 128;

    f32x4 acc[4][4] = {};

    const int srow = w * 32 + (lane >> 2);   // staged row (first 16-row group)
    const int scol = (lane & 3) * 8;
    const u16* ag0 = xb + (size_t)(m0 + srow) * 2048 + scol;
    const u16* bg0 = Wt + (size_t)(n0g + srow) * 2048 + scol;

    for (int kb = 0; kb < 2048; kb += 32) {
        g2l16(ag0 + kb,             &Al[w * 32][0]);
        g2l16(ag0 + kb + 16 * 2048, &Al[w * 32 + 16][0]);
        g2l16(bg0 + kb,             &Bl[w * 32][0]);
        g2l16(bg0 + kb + 16 * 2048, &Bl[w * 32 + 16][0]);
        __syncthreads();

        bf16x8 af[4], bfr[4];
        #pragma unroll
        for (int m = 0; m < 4; ++m)
            af[m] = ld_bf8(&Al[wm * 64 + m * 16 + (lane & 15)][(lane >> 4) * 8]);
        #pragma unroll
        for (int n = 0; n < 4; ++n)
            bfr[n] = ld_bf8(&Bl[wn * 64 + n * 16 + (lane & 15)][(lane >> 4) * 8]);
        #pragma unroll
        for (int m = 0; m < 4; ++m)
            #pragma unroll
            for (int n = 0; n < 4; ++n)
                acc[m][n] = __builtin_amdgcn_mfma_f32_16x16x32_bf16(af[m], bfr[n], acc[m][n], 0, 0, 0);
        __syncthreads();
    }

    const int r0 = (lane >> 4) * 4;
    const int c0 = lane & 15;
    #pragma unroll
    for (int m = 0; m < 4; ++m) {
        #pragma unroll
        for (int n = 0; n < 4; ++n) {
            #pragma unroll
            for (int r = 0; r < 4; ++r) {
                int rw = m0 + wm * 64 + m * 16 + r0 + r;
                int col = n0g + wn * 64 + n * 16 + c0;
                float v = acc[m][n][r];
                int b = rw >> 11, t = rw & 2047;
                if (col < 2048) {
                    int h = col >> 6, d = col & 63;
                    Qb[(((size_t)b * 32 + h) * 2048 + t) * 64 + d] = f2bf(v);
                } else if (col < 2560) {
                    int c2 = col - 2048; int hk = c2 >> 6, d = c2 & 63;
                    Kb[(((size_t)b * 8 + hk) * 2048 + t) * 64 + d] = f2bf(v);
                } else {
                    int c2 = col - 2560; int hk = c2 >> 6, d = c2 & 63;
                    Vb[(((size_t)b * 8 + hk) * 2048 + t) * 64 + d] = f2bf(v);
                }
            }
        }
    }
}

// ---------------- RoPE in-place on Q and K ----------------
__global__ __launch_bounds__(256)
void rope_kernel(u16* __restrict__ Qb, u16* __restrict__ Kb)
{
    const int QP = 2 * 32 * 2048 * 32;
    const int KP = 2 * 8 * 2048 * 32;
    int idx = blockIdx.x * 256 + threadIdx.x;
    if (idx >= QP + KP) return;
    u16* buf; int p;
    if (idx < QP) { buf = Qb; p = idx; } else { buf = Kb; p = idx - QP; }
    int dp = p & 31;
    int t = (p >> 5) & 2047;
    int bh = p >> 16;
    size_t base = ((size_t)bh * 2048 + t) * 64 + dp;
    float x1 = bf2f(buf[base]);
    float x2 = bf2f(buf[base + 32]);
    float inv_freq = __expf(-dp * 0.28782313662425574f); // ln(10000)/32
    float ang = (float)t * inv_freq;
    float s, c;
    sincosf(ang, &s, &c);
    buf[base]      = f2bf(x1 * c - x2 * s);
    buf[base + 32] = f2bf(x2 * c + x1 * s);
}

// ---------------- V transpose: (b,hk,t,d) -> (b,hk,d,t) ----------------
__global__ __launch_bounds__(256)
void vtrans(const u16* __restrict__ Vb, u16* __restrict__ Vt)
{
    __shared__ __align__(16) u16 tile[64][68];
    const int tid = threadIdx.x;
    const int t0 = blockIdx.x * 64;
    const size_t base = (size_t)blockIdx.y * 2048 * 64;
    {
        int r = tid >> 2, c0 = (tid & 3) * 16;
        const u16* src = Vb + base + (size_t)(t0 + r) * 64 + c0;
        *(u16x8*)&tile[r][c0]     = *(const u16x8*)src;
        *(u16x8*)&tile[r][c0 + 8] = *(const u16x8*)(src + 8);
    }
    __syncthreads();
    {
        int d = tid >> 2, j0 = (tid & 3) * 16;
        u16x8 o0, o1;
        #pragma unroll
        for (int i = 0; i < 8; ++i) o0[i] = tile[j0 + i][d];
        #pragma unroll
        for (int i = 0; i < 8; ++i) o1[i] = tile[j0 + 8 + i][d];
        u16* dst = Vt + base + (size_t)d * 2048 + t0 + j0;
        *(u16x8*)dst       = o0;
        *(u16x8*)(dst + 8) = o1;
    }
}

// ---------------- Flash attention: swapped QK^T, in-register softmax ----------------
__global__ __launch_bounds__(256)
void attn_kernel(const u16* __restrict__ Qb, const u16* __restrict__ Kb,
                 const u16* __restrict__ Vt, u16* __restrict__ AO)
{
    __shared__ __align__(16) u16 Kl[64][72];
    __shared__ __align__(16) u16 Vl[64][72];    // Vl[d][j]
    __shared__ __align__(16) u16 Pl[4][16][72]; // per-wave [q][k]

    const int tid = threadIdx.x;
    const int lane = tid & 63;
    const int w = tid >> 6;
    const int q = lane & 15;     // this lane's q-row (stats owner)
    const int hq = lane >> 4;    // quarter-lane group
    const int q0 = blockIdx.x * 64;
    const int bh = blockIdx.y;
    const int b = bh >> 5, h = bh & 31;
    const int hk = h >> 2;
    const size_t qbase  = (size_t)bh * 2048 * 64;
    const size_t kvbase = ((size_t)b * 8 + hk) * 2048 * 64;

    const int sj = tid >> 2;
    const int sd = (tid & 3) * 16;

    // Q fragment (B-operand: col=q, k=d), pre-scaled by 1/8
    bf16x8 qf0, qf1;
    {
        const u16* qp = Qb + qbase + (size_t)(q0 + w * 16 + q) * 64 + hq * 8;
        u16x8 r0 = *(const u16x8*)qp;
        u16x8 r1 = *(const u16x8*)(qp + 32);
        u16x8 q0s, q1s;
        #pragma unroll
        for (int e = 0; e < 8; ++e) {
            q0s[e] = f2bf(bf2f(r0[e]) * 0.125f);
            q1s[e] = f2bf(bf2f(r1[e]) * 0.125f);
        }
        qf0 = __builtin_bit_cast(bf16x8, q0s);
        qf1 = __builtin_bit_cast(bf16x8, q1s);
    }

    float mrun = -1e20f, lrun = 0.f;
    f32x4 o[4] = {};

    int kbeg = q0 - (WINDOW - 1);
    if (kbeg < 0) kbeg = 0;
    kbeg &= ~63;
    const int kend = q0 + 64;

    const int wrow_min = q0 + w * 16;
    const int wrow_max = wrow_min + 15;
    const int iq = wrow_min + q;       // absolute q-row of this lane

    // prologue: stage first tile
    u16x8 kr0, kr1, vr0, vr1;
    {
        const u16* kg = Kb + kvbase + (size_t)(kbeg + sj) * 64 + sd;
        kr0 = *(const u16x8*)kg;
        kr1 = *(const u16x8*)(kg + 8);
        const u16* vg = Vt + kvbase + (size_t)sj * 2048 + kbeg + sd;
        vr0 = *(const u16x8*)vg;
        vr1 = *(const u16x8*)(vg + 8);
    }
    *(u16x8*)&Kl[sj][sd]     = kr0;
    *(u16x8*)&Kl[sj][sd + 8] = kr1;
    *(u16x8*)&Vl[sj][sd]     = vr0;
    *(u16x8*)&Vl[sj][sd + 8] = vr1;
    __syncthreads();

    for (int k0 = kbeg; k0 < kend; k0 += 64) {
        const bool has_next = (k0 + 64 < kend);
        if (has_next) {
            const u16* kg = Kb + kvbase + (size_t)(k0 + 64 + sj) * 64 + sd;
            kr0 = *(const u16x8*)kg;
            kr1 = *(const u16x8*)(kg + 8);
            const u16* vg = Vt + kvbase + (size_t)sj * 2048 + k0 + 64 + sd;
            vr0 = *(const u16x8*)vg;
            vr1 = *(const u16x8*)(vg + 8);
        }

        bool active = (k0 <= wrow_max) && (k0 + 63 >= wrow_min - (WINDOW - 1));
        if (active) {
            // ---- S^T = K Q : s[nf][r] = S[k0 + nf*16 + hq*4 + r][q] ----
            f32x4 s[4];
            #pragma unroll
            for (int nf = 0; nf < 4; ++nf) {
                bf16x8 kb0 = ld_bf8(&Kl[nf * 16 + q][hq * 8]);
                bf16x8 kb1 = ld_bf8(&Kl[nf * 16 + q][32 + hq * 8]);
                f32x4 a = {};
                a = __builtin_amdgcn_mfma_f32_16x16x32_bf16(kb0, qf0, a, 0, 0, 0);
                a = __builtin_amdgcn_mfma_f32_16x16x32_bf16(kb1, qf1, a, 0, 0, 0);
                s[nf] = a;
            }
            // s fragment index: row(key) = nf*16 + hq*4 + r, col(q) = lane&15
            bool need_causal = (k0 + 63 > wrow_min);
            bool need_window = (wrow_max - k0) >= WINDOW;
            if (need_causal || need_window) {
                #pragma unroll
                for (int nf = 0; nf < 4; ++nf) {
                    #pragma unroll
                    for (int r = 0; r < 4; ++r) {
                        int j = k0 + nf * 16 + hq * 4 + r;
                        bool ok = (j <= iq) && (iq - j < WINDOW);
                        if (!ok) s[nf][r] = -1e30f;
                    }
                }
            }
            // ---- row max: 15 in-register + 2 shuffles ----
            float tmax = s[0][0];
            #pragma unroll
            for (int nf = 0; nf < 4; ++nf)
                #pragma unroll
                for (int r = 0; r < 4; ++r) tmax = fmaxf(tmax, s[nf][r]);
            tmax = fmaxf(tmax, __shfl_xor(tmax, 16));
            tmax = fmaxf(tmax, __shfl_xor(tmax, 32));

            bool skip = __all(tmax <= mrun);
            float mnew = skip ? mrun : fmaxf(mrun, tmax);

            // ---- P = exp(S - m): 4x ds_write_b64 into Pl[q][k] ----
            float tsum = 0.f;
            #pragma unroll
            for (int nf = 0; nf < 4; ++nf) {
                float p0 = __expf(s[nf][0] - mnew);
                float p1 = __expf(s[nf][1] - mnew);
                float p2 = __expf(s[nf][2] - mnew);
                float p3 = __expf(s[nf][3] - mnew);
                tsum += (p0 + p1) + (p2 + p3);
                u16x4 pw = { f2bf(p0), f2bf(p1), f2bf(p2), f2bf(p3) };
                *(u16x4*)&Pl[w][q][nf * 16 + hq * 4] = pw;
            }
            tsum += __shfl_xor(tsum, 16);
            tsum += __shfl_xor(tsum, 32);

            if (skip) {
                lrun += tsum;
            } else {
                float sc = __expf(mrun - mnew);
                mrun = mnew;
                lrun = lrun * sc + tsum;
                // redistribute sc (per q=lane&15) to o's rows (q' = hq*4+r)
                float osc[4];
                #pragma unroll
                for (int r = 0; r < 4; ++r)
                    osc[r] = __shfl(sc, (lane & 48) + hq * 4 + r);
                #pragma unroll
                for (int nf = 0; nf < 4; ++nf)
                    #pragma unroll
                    for (int r = 0; r < 4; ++r)
                        o[nf][r] *= osc[r];
            }

            // ---- O += P @ V ----
            bf16x8 pa0 = ld_bf8(&Pl[w][q][hq * 8]);
            bf16x8 pa1 = ld_bf8(&Pl[w][q][32 + hq * 8]);
            #pragma unroll
            for (int nf = 0; nf < 4; ++nf) {
                bf16x8 vb0 = ld_bf8(&Vl[nf * 16 + q][hq * 8]);
                bf16x8 vb1 = ld_bf8(&Vl[nf * 16 + q][32 + hq * 8]);
                o[nf] = __builtin_amdgcn_mfma_f32_16x16x32_bf16(pa0, vb0, o[nf], 0, 0, 0);
                o[nf] = __builtin_amdgcn_mfma_f32_16x16x32_bf16(pa1, vb1, o[nf], 0, 0, 0);
            }
        }
        __syncthreads();
        if (has_next) {
            *(u16x8*)&Kl[sj][sd]     = kr0;
            *(u16x8*)&Kl[sj][sd + 8] = kr1;
            *(u16x8*)&Vl[sj][sd]     = vr0;
            *(u16x8*)&Vl[sj][sd + 8] = vr1;
        }
        __syncthreads();
    }

    // epilogue: o rows are q' = hq*4+r; fetch 1/l for those rows via shuffles
    float linv_own = 1.f / lrun;
    float linv[4];
    #pragma unroll
    for (int r = 0; r < 4; ++r)
        linv[r] = __shfl(linv_own, (lane & 48) + hq * 4 + r);
    #pragma unroll
    for (int nf = 0; nf < 4; ++nf) {
        #pragma unroll
        for (int r = 0; r < 4; ++r) {
            int i = q0 + w * 16 + hq * 4 + r;
            int d = nf * 16 + q;
            AO[((size_t)b * 2048 + i) * 2048 + h * 64 + d] = f2bf(o[nf][r] * linv[r]);
        }
    }
}

// ---------------- Output projection (m97 structure): out = AO_bf16 @ WoT^T ----------------
__global__ __launch_bounds__(256)
void out_gemm(const u16* __restrict__ A, const u16* __restrict__ Wt, float* __restrict__ C)
{
    __shared__ __align__(16) u16 Al[128][32];
    __shared__ __align__(16) u16 Bl[128][32];
    const int tid = threadIdx.x;
    const int lane = tid & 63;
    const int w = tid >> 6;
    const int wm = w >> 1, wn = w & 1;
    const int m0 = blockIdx.x * 128;
    const int n0 = blockIdx.y * 128;

    f32x4 acc[4][4] = {};

    const int srow = w * 32 + (lane >> 2);
    const int scol = (lane & 3) * 8;
    const u16* ag0 = A  + (size_t)(m0 + srow) * 2048 + scol;
    const u16* bg0 = Wt + (size_t)(n0 + srow) * 2048 + scol;

    for (int kb = 0; kb < 2048; kb += 32) {
        g2l16(ag0 + kb,             &Al[w * 32][0]);
        g2l16(ag0 + kb + 16 * 2048, &Al[w * 32 + 16][0]);
        g2l16(bg0 + kb,             &Bl[w * 32][0]);
        g2l16(bg0 + kb + 16 * 2048, &Bl[w * 32 + 16][0]);
        __syncthreads();

        bf16x8 af[4], bfr[4];
        #pragma unroll
        for (int m = 0; m < 4; ++m)
            af[m] = ld_bf8(&Al[wm * 64 + m * 16 + (lane & 15)][(lane >> 4) * 8]);
        #pragma unroll
        for (int n = 0; n < 4; ++n)
            bfr[n] = ld_bf8(&Bl[wn * 64 + n * 16 + (lane & 15)][(lane >> 4) * 8]);
        #pragma unroll
        for (int m = 0; m < 4; ++m)
            #pragma unroll
            for (int n = 0; n < 4; ++n)
                acc[m][n] = __builtin_amdgcn_mfma_f32_16x16x32_bf16(af[m], bfr[n], acc[m][n], 0, 0, 0);
        __syncthreads();
    }

    const int r0 = (lane >> 4) * 4;
    const int c0 = lane & 15;
    #pragma unroll
    for (int m = 0; m < 4; ++m) {
        #pragma unroll
        for (int n = 0; n < 4; ++n) {
            #pragma unroll
            for (int r = 0; r < 4; ++r) {
                int rw = m0 + wm * 64 + m * 16 + r0 + r;
                int col = n0 + wn * 64 + n * 16 + c0;
                C[(size_t)rw * 2048 + col] = acc[m][n][r];
            }
        }
    }
}

extern "C" void kernel_launch(void* const* d_in, const int* in_sizes, int n_in,
                              void* d_out, int out_size, void* d_ws, size_t ws_size,
                              hipStream_t stream)
{
    const float* x  = (const float*)d_in[0];
    const float* Wq = (const float*)d_in[1];
    const float* Wk = (const float*)d_in[2];
    const float* Wv = (const float*)d_in[3];
    const float* Wo = (const float*)d_in[4];
    float* out = (float*)d_out;

    u16* Qb    = (u16*)d_ws;                              //  8,388,608
    u16* Kb    = Qb    + (size_t)8388608;                 //  2,097,152
    u16* Vb    = Kb    + (size_t)2097152;                 //  2,097,152
    u16* Vt    = Vb    + (size_t)2097152;                 //  2,097,152
    u16* AO    = Vt    + (size_t)2097152;                 //  8,388,608
    u16* xb    = AO    + (size_t)8388608;                 //  8,388,608
    u16* WqkvT = xb    + (size_t)8388608;                 //  6,291,456  [3072][2048]
    u16* WoT   = WqkvT + (size_t)6291456;                 //  4,194,304  [2048][2048]

    convert_x<<<4096, 256, 0, stream>>>(x, xb);
    trans_conv<<<dim3(32, 32), 256, 0, stream>>>(Wq, 2048, WqkvT);
    trans_conv<<<dim3(32,  8), 256, 0, stream>>>(Wk,  512, WqkvT + (size_t)2048 * 2048);
    trans_conv<<<dim3(32,  8), 256, 0, stream>>>(Wv,  512, WqkvT + (size_t)2560 * 2048);
    trans_conv<<<dim3(32, 32), 256, 0, stream>>>(Wo, 2048, WoT);

    qkv_gemm<<<dim3(32, 24), 256, 0, stream>>>(xb, WqkvT, Qb, Kb, Vb);
    rope_kernel<<<(4194304 + 1048576) / 256, 256, 0, stream>>>(Qb, Kb);
    vtrans<<<dim3(32, 16), 256, 0, stream>>>(Vb, Vt);
    attn_kernel<<<dim3(32, 64), 256, 0, stream>>>(Qb, Kb, Vt, AO);
    out_gemm<<<dim3(32, 16), 256, 0, stream>>>(AO, WoT, out);
}